// Round 1
// baseline (217.944 us; speedup 1.0000x reference)
//
#include <hip/hip_runtime.h>

#define SZ   256   // image size
#define NPTS 128   // points per batch
#define NB3  6     // bs * ncam = 2*3

// Global normalization over all 6 camera values (jnp .mean()/.max() reduce the
// whole (2,3) array, not per-row).
__device__ __forceinline__ float norm6(const float* __restrict__ v, int idx) {
    float a0 = v[0], a1 = v[1], a2 = v[2], a3 = v[3], a4 = v[4], a5 = v[5];
    float mean = (a0 + a1 + a2 + a3 + a4 + a5) * (1.0f / 6.0f);
    float inv = 1.0f / mean;
    float b0 = a0 * inv, b1 = a1 * inv, b2 = a2 * inv;
    float b3 = a3 * inv, b4 = a4 * inv, b5 = a5 * inv;
    float d = fmaxf(fmaxf(fmaxf(fabsf(b0 - 1.f), fabsf(b1 - 1.f)),
                          fmaxf(fabsf(b2 - 1.f), fabsf(b3 - 1.f))),
                    fmaxf(fabsf(b4 - 1.f), fabsf(b5 - 1.f)));
    float sf = 0.2f / d;                 // d==0 -> inf -> takes 'vi' branch
    float vi = v[idx] * inv;
    return (sf < 1.0f) ? (vi - 1.0f) * sf + 1.0f : vi;
}

__global__ __launch_bounds__(256) void render_kernel(
    const float* __restrict__ points,       // (2,3,128,2)
    const float* __restrict__ sigmas,       // (2,128)
    const float* __restrict__ exponents,    // (2,128)
    const float* __restrict__ intensities,  // (2,128)
    const float* __restrict__ cam_s,        // (2,3)
    const float* __restrict__ cam_e,        // (2,3)
    const float* __restrict__ cam_i,        // (2,3)
    float* __restrict__ masks,              // (6,256,256)
    float* __restrict__ blobs)              // (6,128,256,256)
{
    __shared__ float s_px[NPTS], s_py[NPTS], s_q[NPTS], s_e[NPTS], s_i[NPTS];

    const int b3  = blockIdx.x >> 6;         // [0,6)
    const int yb  = (blockIdx.x & 63) << 2;  // 4 rows per block
    const int tid = threadIdx.x;

    if (tid < NPTS) {
        const int b = b3 / 3;
        const float cs = norm6(cam_s, b3);
        const float ce = norm6(cam_e, b3);
        const float ci = norm6(cam_i, b3);
        float px = points[(b3 * NPTS + tid) * 2 + 0];
        float py = points[(b3 * NPTS + tid) * 2 + 1];
        px = fminf(fmaxf((px - 128.0f) * (1.0f / 128.0f), -1.0f), 1.0f);
        py = fminf(fmaxf((py - 128.0f) * (1.0f / 128.0f), -1.0f), 1.0f);
        const float sg = sigmas[b * NPTS + tid] * cs;
        s_px[tid] = px;
        s_py[tid] = py;
        s_q[tid]  = 1.0f / (2.0f * sg * sg);
        s_e[tid]  = exponents[b * NPTS + tid] * ce;
        s_i[tid]  = intensities[b * NPTS + tid] * ci;
    }
    __syncthreads();

    const int y  = yb + (tid >> 6);
    const int x0 = (tid & 63) << 2;
    const float gy  = -1.0f + (float)y * (2.0f / 255.0f);
    const float gx0 = -1.0f + (float)(x0    ) * (2.0f / 255.0f);
    const float gx1 = -1.0f + (float)(x0 + 1) * (2.0f / 255.0f);
    const float gx2 = -1.0f + (float)(x0 + 2) * (2.0f / 255.0f);
    const float gx3 = -1.0f + (float)(x0 + 3) * (2.0f / 255.0f);

    float m0 = 0.f, m1 = 0.f, m2 = 0.f, m3 = 0.f;
    float4* bptr = (float4*)(blobs + (size_t)b3 * NPTS * SZ * SZ
                                   + (size_t)y * SZ + x0);
    const size_t pstride = (SZ * SZ) / 4;   // plane stride in float4 units

    #pragma unroll 4
    for (int n = 0; n < NPTS; ++n) {
        const float px = s_px[n], py = s_py[n];
        const float q  = s_q[n],  e  = s_e[n], it = s_i[n];
        const float dy  = gy - py;
        const float dy2 = dy * dy;
        const float d0 = gx0 - px, d1 = gx1 - px, d2 = gx2 - px, d3 = gx3 - px;
        const float u0 = fmaf(d0, d0, dy2) * q;
        const float u1 = fmaf(d1, d1, dy2) * q;
        const float u2 = fmaf(d2, d2, dy2) * q;
        const float u3 = fmaf(d3, d3, dy2) * q;
        // blob = exp(-(u^e)); u==0 -> log=-inf -> t=0 -> blob=1 (matches 0**e)
        const float bl0 = __expf(-__expf(e * __logf(u0)));
        const float bl1 = __expf(-__expf(e * __logf(u1)));
        const float bl2 = __expf(-__expf(e * __logf(u2)));
        const float bl3 = __expf(-__expf(e * __logf(u3)));
        bptr[(size_t)n * pstride] = make_float4(bl0, bl1, bl2, bl3);
        m0 = fmaxf(m0, bl0 * it);
        m1 = fmaxf(m1, bl1 * it);
        m2 = fmaxf(m2, bl2 * it);
        m3 = fmaxf(m3, bl3 * it);
    }

    float4* mptr = (float4*)(masks + (size_t)b3 * SZ * SZ + (size_t)y * SZ + x0);
    *mptr = make_float4(fminf(m0, 1.f), fminf(m1, 1.f),
                        fminf(m2, 1.f), fminf(m3, 1.f));
}

extern "C" void kernel_launch(void* const* d_in, const int* in_sizes, int n_in,
                              void* d_out, int out_size, void* d_ws, size_t ws_size,
                              hipStream_t stream) {
    const float* points      = (const float*)d_in[0];
    const float* sigmas      = (const float*)d_in[1];
    const float* exponents   = (const float*)d_in[2];
    const float* intensities = (const float*)d_in[3];
    const float* cam_s       = (const float*)d_in[4];
    const float* cam_e       = (const float*)d_in[5];
    const float* cam_i       = (const float*)d_in[6];

    float* out   = (float*)d_out;
    float* masks = out;                       // 6*256*256 = 393216 floats
    float* blobs = out + NB3 * SZ * SZ;       // 6*128*256*256 floats

    hipLaunchKernelGGL(render_kernel, dim3(NB3 * 64), dim3(256), 0, stream,
                       points, sigmas, exponents, intensities,
                       cam_s, cam_e, cam_i, masks, blobs);
}

// Round 3
// 207.450 us; speedup vs baseline: 1.0506x; 1.0506x over previous
//
#include <hip/hip_runtime.h>

#define SZ   256   // image size
#define NPTS 128   // points per batch
#define NB3  6     // bs * ncam = 2*3

// v_exp_f32 / v_log_f32: base-2 exp and log, single-instruction on gfx950.
#define EXP2F(x) __builtin_amdgcn_exp2f(x)
#define LOG2F(x) __builtin_amdgcn_logf(x)

// Global normalization over all 6 camera values (jnp .mean()/.max() reduce the
// whole (2,3) array, not per-row).
__device__ __forceinline__ float norm6(const float* __restrict__ v, int idx) {
    float a0 = v[0], a1 = v[1], a2 = v[2], a3 = v[3], a4 = v[4], a5 = v[5];
    float mean = (a0 + a1 + a2 + a3 + a4 + a5) * (1.0f / 6.0f);
    float inv = 1.0f / mean;
    float b0 = a0 * inv, b1 = a1 * inv, b2 = a2 * inv;
    float b3 = a3 * inv, b4 = a4 * inv, b5 = a5 * inv;
    float d = fmaxf(fmaxf(fmaxf(fabsf(b0 - 1.f), fabsf(b1 - 1.f)),
                          fmaxf(fabsf(b2 - 1.f), fabsf(b3 - 1.f))),
                    fmaxf(fabsf(b4 - 1.f), fabsf(b5 - 1.f)));
    float sf = 0.2f / d;                 // d==0 -> inf -> takes 'vi' branch
    float vi = v[idx] * inv;
    return (sf < 1.0f) ? (vi - 1.0f) * sf + 1.0f : vi;
}

// blob = exp(-(dst*q)^e) = exp2(-exp2(e*log2(dst) + c2)),
//   c2 = e*log2(q) + log2(log2(e))
__global__ __launch_bounds__(256) void render_kernel(
    const float* __restrict__ points,       // (2,3,128,2)
    const float* __restrict__ sigmas,       // (2,128)
    const float* __restrict__ exponents,    // (2,128)
    const float* __restrict__ intensities,  // (2,128)
    const float* __restrict__ cam_s,        // (2,3)
    const float* __restrict__ cam_e,        // (2,3)
    const float* __restrict__ cam_i,        // (2,3)
    float* __restrict__ masks,              // (6,256,256)
    float* __restrict__ blobs)              // (6,128,256,256)
{
    __shared__ float4 s_p[NPTS];   // px, py, e, c2
    __shared__ float  s_i[NPTS];   // intensity

    const int b3  = blockIdx.x >> 8;   // [0,6)
    const int y   = blockIdx.x & 255;  // row
    const int tid = threadIdx.x;       // x pixel

    if (tid < NPTS) {
        const int b = b3 / 3;
        const float cs = norm6(cam_s, b3);
        const float ce = norm6(cam_e, b3);
        const float ci = norm6(cam_i, b3);
        float px = points[(b3 * NPTS + tid) * 2 + 0];
        float py = points[(b3 * NPTS + tid) * 2 + 1];
        px = fminf(fmaxf((px - 128.0f) * (1.0f / 128.0f), -1.0f), 1.0f);
        py = fminf(fmaxf((py - 128.0f) * (1.0f / 128.0f), -1.0f), 1.0f);
        const float sg = sigmas[b * NPTS + tid] * cs;
        const float e  = exponents[b * NPTS + tid] * ce;
        const float q  = 1.0f / (2.0f * sg * sg);
        const float C  = 0.5287663729448977f;           // log2(log2(e))
        const float c2 = fmaf(e, LOG2F(q), C);
        s_p[tid] = make_float4(px, py, e, c2);
        s_i[tid] = intensities[b * NPTS + tid] * ci;
    }
    __syncthreads();

    const float gy = -1.0f + (float)y   * (2.0f / 255.0f);
    const float gx = -1.0f + (float)tid * (2.0f / 255.0f);

    float m = 0.0f;
    float* bptr = blobs + (size_t)b3 * NPTS * SZ * SZ + (size_t)y * SZ + tid;

    #pragma unroll 4
    for (int n = 0; n < NPTS; ++n) {
        const float4 p = s_p[n];
        const float dx = gx - p.x;
        const float dy = gy - p.y;
        const float u  = fmaf(dx, dx, dy * dy);          // squared distance
        // l = e*log2(u) + c2 ; t = 2^l ; blob = 2^(-t)
        const float l  = fmaf(p.z, LOG2F(u), p.w);
        const float t  = EXP2F(l);
        const float bl = EXP2F(-t);                      // u==0 -> t=0 -> bl=1
        bptr[(size_t)n * (SZ * SZ)] = bl;
        m = fmaxf(m, bl * s_i[n]);
    }

    masks[(size_t)b3 * SZ * SZ + (size_t)y * SZ + tid] = fminf(m, 1.0f);
}

extern "C" void kernel_launch(void* const* d_in, const int* in_sizes, int n_in,
                              void* d_out, int out_size, void* d_ws, size_t ws_size,
                              hipStream_t stream) {
    const float* points      = (const float*)d_in[0];
    const float* sigmas      = (const float*)d_in[1];
    const float* exponents   = (const float*)d_in[2];
    const float* intensities = (const float*)d_in[3];
    const float* cam_s       = (const float*)d_in[4];
    const float* cam_e       = (const float*)d_in[5];
    const float* cam_i       = (const float*)d_in[6];

    float* out   = (float*)d_out;
    float* masks = out;                       // 6*256*256 = 393216 floats
    float* blobs = out + NB3 * SZ * SZ;       // 6*128*256*256 floats

    hipLaunchKernelGGL(render_kernel, dim3(NB3 * SZ), dim3(256), 0, stream,
                       points, sigmas, exponents, intensities,
                       cam_s, cam_e, cam_i, masks, blobs);
}